// Round 13
// baseline (418.621 us; speedup 1.0000x reference)
//
#include <hip/hip_runtime.h>
#include <hip/hip_bf16.h>

typedef unsigned short U16;
typedef __attribute__((ext_vector_type(8))) short bf16x8;
typedef __attribute__((ext_vector_type(4))) float f32x4;
typedef __attribute__((ext_vector_type(4))) unsigned short u16x4;

#define BB 2
#define SS 2048
#define WW 1024
#define HH 16
#define CC 64
#define MTOT (BB*SS)                    // 4096
// SCALE = 1/64^0.25; QK_SCALE = SCALE * sqrt(log2(e)) -> logits in log2 units
#define QK_SCALE 0.4246609001440095f
#define RESCALE_THR 8.0f

__device__ __forceinline__ U16 f2bf(float f) {
  __hip_bfloat16 b = __float2bfloat16(f);       // native RNE cast (m240)
  return *reinterpret_cast<U16*>(&b);
}
__device__ __forceinline__ float bf2f(U16 h) {
  return __uint_as_float(((unsigned int)h) << 16);
}

// async global->LDS, 16B/lane; LDS dest = wave-uniform base + lane*16 (linear!)
// Swizzled layouts via inverse-swizzled per-lane GLOBAL source (rule 21).
#define GLD16(gp, lp) __builtin_amdgcn_global_load_lds( \
    (const __attribute__((address_space(1))) unsigned int*)(gp), \
    (__attribute__((address_space(3))) unsigned int*)(lp), 16, 0, 0)

#define MFMA(a,b,c) __builtin_amdgcn_mfma_f32_16x16x32_bf16(a,b,c,0,0,0)

// ---------------------------------------------------------------- split convert
__global__ void cvt_split(const float* __restrict__ in, U16* __restrict__ hi,
                          U16* __restrict__ lo, int n4) {
  int i = blockIdx.x * blockDim.x + threadIdx.x;
  if (i < n4) {
    float4 v = reinterpret_cast<const float4*>(in)[i];
    float vv[4] = {v.x, v.y, v.z, v.w};
    u16x4 h, l;
#pragma unroll
    for (int j = 0; j < 4; ++j) {
      U16 hb = f2bf(vv[j]);
      h[j] = hb;
      l[j] = f2bf(vv[j] - bf2f(hb));
    }
    reinterpret_cast<u16x4*>(hi)[i] = h;
    reinterpret_cast<u16x4*>(lo)[i] = l;
  }
}

// ---------------------------------------------------------------- split GEMM 128x128, BK=32
// C = (Ah+Al)*(Bh+Bl)^T + bias via Ah*Bh + Ah*Bl + Al*Bh.
// HI tiles staged via global_load_lds ([128][32], swizzle blk^=(row>>1)&3);
// LO fragments read DIRECTLY global->reg (coalesced 16B/lane, L2-resident).
template<int EPI>
__global__ __launch_bounds__(256) void gemm_split(
    const U16* __restrict__ Ah, const U16* __restrict__ Al,
    const U16* __restrict__ Bh, const U16* __restrict__ Bl,
    const float* __restrict__ bias, int K, int N,
    float* __restrict__ out,
    U16* __restrict__ Qh, U16* __restrict__ Ql,
    U16* __restrict__ Kh, U16* __restrict__ Kl, U16* __restrict__ Vt)
{
  __shared__ U16 AsH[128*32], BsH[128*32];
  const int tid  = threadIdx.x;
  const int lane = tid & 63, w = tid >> 6;
  const int wr = w >> 1, wc = w & 1;
  const int g = lane >> 4, lr = lane & 15;
  const int bm = blockIdx.x, bn = blockIdx.y;

  f32x4 acc[4][4] = {};

  for (int k0 = 0; k0 < K; k0 += 32) {
#pragma unroll
    for (int i = 0; i < 2; ++i) {
      const int rowT = i*64 + (tid >> 2);                 // tile row 0..127
      const int sblk = (tid & 3) ^ ((rowT >> 1) & 3);     // inverse-swizzled source block
      const size_t ga = (size_t)(bm*128 + rowT) * K + k0 + sblk*8;
      const size_t gb = (size_t)(bn*128 + rowT) * K + k0 + sblk*8;
      const int lb = i*2048 + w*512;
      GLD16(Ah + ga, &AsH[lb]);
      GLD16(Bh + gb, &BsH[lb]);
    }
    __syncthreads();

    bf16x8 ah[4], bh[4], al[4], bl[4];
#pragma unroll
    for (int mi = 0; mi < 4; ++mi) {
      const int row = wr*64 + mi*16 + lr;
      ah[mi] = *reinterpret_cast<const bf16x8*>(&AsH[row*32 + ((g ^ ((row >> 1) & 3)) * 8)]);
      al[mi] = *reinterpret_cast<const bf16x8*>(Al + (size_t)(bm*128 + row) * K + k0 + g*8);
    }
#pragma unroll
    for (int ni = 0; ni < 4; ++ni) {
      const int row = wc*64 + ni*16 + lr;
      bh[ni] = *reinterpret_cast<const bf16x8*>(&BsH[row*32 + ((g ^ ((row >> 1) & 3)) * 8)]);
      bl[ni] = *reinterpret_cast<const bf16x8*>(Bl + (size_t)(bn*128 + row) * K + k0 + g*8);
    }
    // hi*hi first — independent of lo loads, hides their L2 latency
#pragma unroll
    for (int ni = 0; ni < 4; ++ni)
#pragma unroll
      for (int mi = 0; mi < 4; ++mi)
        acc[mi][ni] = MFMA(ah[mi], bh[ni], acc[mi][ni]);
#pragma unroll
    for (int ni = 0; ni < 4; ++ni)
#pragma unroll
      for (int mi = 0; mi < 4; ++mi) {
        acc[mi][ni] = MFMA(ah[mi], bl[ni], acc[mi][ni]);
        acc[mi][ni] = MFMA(al[mi], bh[ni], acc[mi][ni]);
      }
    __syncthreads();
  }

  // epilogue; D layout (m89): row = 4*(lane>>4)+reg, col = lane&15
#pragma unroll
  for (int mi = 0; mi < 4; ++mi) {
#pragma unroll
    for (int ni = 0; ni < 4; ++ni) {
#pragma unroll
      for (int r = 0; r < 4; ++r) {
        const int grow = bm*128 + wr*64 + mi*16 + 4*g + r;
        const int gcol = bn*128 + wc*64 + ni*16 + lr;
        const float val = acc[mi][ni][r] + bias[gcol];
        if (EPI == 0) {
          const int b = grow >> 11, s = grow & 2047;
          const int h = gcol / 192;
          const int rem = gcol - h * 192;
          const int t = rem >> 6, c = rem & 63;
          const size_t bh_ = (size_t)(b * HH + h);
          if (t == 2) {
            Vt[(bh_ * CC + c) * SS + s] = f2bf(val);
          } else {
            const float sv = val * QK_SCALE;   // symmetric scale * sqrt(log2e)
            const U16 hb = f2bf(sv);
            const U16 lb = f2bf(sv - bf2f(hb));
            const size_t idx = (bh_ * SS + s) * CC + c;
            if (t == 0) { Qh[idx] = hb; Ql[idx] = lb; }
            else        { Kh[idx] = hb; Kl[idx] = lb; }
          }
        } else {
          out[(size_t)grow * N + gcol] = val;
        }
      }
    }
  }
}

// ---------------------------------------------------------------- flash attention
// grid: (B*H, S/64). 4 waves x 16 q-rows. KV tiles of 64. Logits in log2 units.
// K/V LDS tiles [64][64] bf16, swizzle blk^=(row&7). Defer-max THR=8 (T13).
__global__ __launch_bounds__(256) void attn_kernel(
    const U16* __restrict__ Qh, const U16* __restrict__ Ql,
    const U16* __restrict__ Kh, const U16* __restrict__ Kl,
    const U16* __restrict__ Vtb, U16* __restrict__ Obh, U16* __restrict__ Obl)
{
  __shared__ U16 KsH[64*64];
  __shared__ U16 KsL[64*64];
  __shared__ U16 Vts[64*64];          // [c][s_local]
  __shared__ U16 Ps [4][16*72];       // per-wave P tile, stride 72

  const int tid  = threadIdx.x;
  const int lane = tid & 63, w = tid >> 6;
  const int g = lane >> 4, lr = lane & 15;
  const int bh = blockIdx.x;          // 0..31
  const int qt = blockIdx.y;          // 0..31

  const U16* QhP = Qh  + (size_t)bh * SS * CC;
  const U16* QlP = Ql  + (size_t)bh * SS * CC;
  const U16* KhP = Kh  + (size_t)bh * SS * CC;
  const U16* KlP = Kl  + (size_t)bh * SS * CC;
  const U16* Vh  = Vtb + (size_t)bh * CC * SS;

  const int q0 = qt * 64 + w * 16;

  bf16x8 qfh[2], qfl[2];
#pragma unroll
  for (int kk = 0; kk < 2; ++kk) {
    qfh[kk] = *reinterpret_cast<const bf16x8*>(&QhP[(size_t)(q0 + lr) * CC + kk*32 + g*8]);
    qfl[kk] = *reinterpret_cast<const bf16x8*>(&QlP[(size_t)(q0 + lr) * CC + kk*32 + g*8]);
  }

  float m[4], l[4];
  f32x4 o[4];
#pragma unroll
  for (int r = 0; r < 4; ++r) { m[r] = -1e30f; l[r] = 0.f; }
#pragma unroll
  for (int cs = 0; cs < 4; ++cs) o[cs] = (f32x4){0.f, 0.f, 0.f, 0.f};

  for (int kv = 0; kv < SS; kv += 64) {
#pragma unroll
    for (int i = 0; i < 2; ++i) {
      const int t2   = i*256 + tid;
      const int row  = t2 >> 3;
      const int sblk = (t2 & 7) ^ (row & 7);
      const int lb   = (i*256 + w*64) * 8;
      GLD16(KhP + (size_t)(kv + row) * CC + sblk*8, &KsH[lb]);
      GLD16(KlP + (size_t)(kv + row) * CC + sblk*8, &KsL[lb]);
      GLD16(Vh  + (size_t)row * SS + kv + sblk*8,   &Vts[lb]);
    }
    __syncthreads();

    // S = Q K^T (split)
    f32x4 sacc[4];
#pragma unroll
    for (int ns = 0; ns < 4; ++ns) {
      f32x4 a = {0.f, 0.f, 0.f, 0.f};
      const int krow = ns*16 + lr;
#pragma unroll
      for (int kk = 0; kk < 2; ++kk) {
        const int so = krow*64 + (((kk*4 + g) ^ (krow & 7)) * 8);
        bf16x8 kfh = *reinterpret_cast<const bf16x8*>(&KsH[so]);
        bf16x8 kfl = *reinterpret_cast<const bf16x8*>(&KsL[so]);
        a = MFMA(qfh[kk], kfh, a);
        a = MFMA(qfh[kk], kfl, a);
        a = MFMA(qfl[kk], kfh, a);
      }
      sacc[ns] = a;
    }

    // online softmax in log2 units; D row = 4*g + r, col = ns*16 + lr
    float mx[4];
#pragma unroll
    for (int r = 0; r < 4; ++r) {
      float v = fmaxf(fmaxf(sacc[0][r], sacc[1][r]), fmaxf(sacc[2][r], sacc[3][r]));
#pragma unroll
      for (int off = 1; off < 16; off <<= 1) v = fmaxf(v, __shfl_xor(v, off, 64));
      mx[r] = v;
    }
    float pr[4][4];
    const bool nog = (mx[0] <= m[0] + RESCALE_THR) & (mx[1] <= m[1] + RESCALE_THR) &
                     (mx[2] <= m[2] + RESCALE_THR) & (mx[3] <= m[3] + RESCALE_THR);
    if (__all(nog)) {
      // defer-max: no rescale, P bounded by 2^THR
#pragma unroll
      for (int r = 0; r < 4; ++r) {
        float ps = 0.f;
#pragma unroll
        for (int ns = 0; ns < 4; ++ns) {
          const float p = exp2f(sacc[ns][r] - m[r]);
          pr[ns][r] = p; ps += p;
        }
#pragma unroll
        for (int off = 1; off < 16; off <<= 1) ps += __shfl_xor(ps, off, 64);
        l[r] += ps;
      }
    } else {
#pragma unroll
      for (int r = 0; r < 4; ++r) {
        const float mn   = fmaxf(m[r], mx[r]);
        const float corr = exp2f(m[r] - mn);
        float ps = 0.f;
#pragma unroll
        for (int ns = 0; ns < 4; ++ns) {
          const float p = exp2f(sacc[ns][r] - mn);
          pr[ns][r] = p; ps += p;
        }
#pragma unroll
        for (int off = 1; off < 16; off <<= 1) ps += __shfl_xor(ps, off, 64);
        l[r] = l[r] * corr + ps;
        m[r] = mn;
#pragma unroll
        for (int cs = 0; cs < 4; ++cs) o[cs][r] *= corr;
      }
    }

    // P -> bf16 -> per-wave LDS
#pragma unroll
    for (int ns = 0; ns < 4; ++ns)
#pragma unroll
      for (int r = 0; r < 4; ++r)
        Ps[w][(4*g + r)*72 + ns*16 + lr] = f2bf(pr[ns][r]);
    asm volatile("s_waitcnt lgkmcnt(0)" ::: "memory");
    __builtin_amdgcn_sched_barrier(0);

    // O += P V  (pf cs-invariant: hoisted)
    bf16x8 pf[2];
#pragma unroll
    for (int kk = 0; kk < 2; ++kk)
      pf[kk] = *reinterpret_cast<const bf16x8*>(&Ps[w][lr*72 + kk*32 + g*8]);
#pragma unroll
    for (int cs = 0; cs < 4; ++cs) {
      f32x4 a = o[cs];
      const int vrow = cs*16 + lr;
#pragma unroll
      for (int kk = 0; kk < 2; ++kk) {
        const int so = vrow*64 + (((kk*4 + g) ^ (vrow & 7)) * 8);
        bf16x8 vf = *reinterpret_cast<const bf16x8*>(&Vts[so]);
        a = MFMA(pf[kk], vf, a);
      }
      o[cs] = a;
    }
    __syncthreads();
  }

  // finalize: Ob (hi/lo) at [b][s][h*64+c]
  const int b = bh >> 4, h = bh & 15;
#pragma unroll
  for (int r = 0; r < 4; ++r) {
    const float inv = 1.0f / l[r];
    const int qg = q0 + 4*g + r;
#pragma unroll
    for (int cs = 0; cs < 4; ++cs) {
      const float ov = o[cs][r] * inv;
      const size_t idx = ((size_t)(b*SS + qg)) * WW + h*CC + cs*16 + lr;
      const U16 hb = f2bf(ov);
      Obh[idx] = hb;
      Obl[idx] = f2bf(ov - bf2f(hb));
    }
  }
}

// ---------------------------------------------------------------- launch
extern "C" void kernel_launch(void* const* d_in, const int* in_sizes, int n_in,
                              void* d_out, int out_size, void* d_ws, size_t ws_size,
                              hipStream_t stream)
{
  const float* x      = (const float*)d_in[0];
  const float* w_qkv  = (const float*)d_in[1];
  const float* b_qkv  = (const float*)d_in[2];
  const float* w_proj = (const float*)d_in[3];
  const float* b_proj = (const float*)d_in[4];
  float* out = (float*)d_out;

  U16* ws = (U16*)d_ws;
  U16* xh      = ws;                                   // 4096*1024
  U16* xl      = xh     + (size_t)MTOT*WW;
  U16* wqkvh   = xl     + (size_t)MTOT*WW;             // 3072*1024
  U16* wqkvl   = wqkvh  + (size_t)3*WW*WW;
  U16* wprojh  = wqkvl  + (size_t)3*WW*WW;             // 1024*1024
  U16* wprojl  = wprojh + (size_t)WW*WW;
  U16* Qhb     = wprojl + (size_t)WW*WW;               // [b][h][s][c]
  U16* Qlb     = Qhb    + (size_t)BB*HH*SS*CC;
  U16* Khb     = Qlb    + (size_t)BB*HH*SS*CC;
  U16* Klb     = Khb    + (size_t)BB*HH*SS*CC;
  U16* Vtb     = Klb    + (size_t)BB*HH*SS*CC;         // [b][h][c][s]
  U16* Obh     = xh;                                   // alias x (consumed by GEMM1)
  U16* Obl     = xl;

  int n4 = MTOT*WW/4;
  cvt_split<<<(n4 + 255)/256, 256, 0, stream>>>(x, xh, xl, n4);
  n4 = 3*WW*WW/4;
  cvt_split<<<(n4 + 255)/256, 256, 0, stream>>>(w_qkv, wqkvh, wqkvl, n4);
  n4 = WW*WW/4;
  cvt_split<<<(n4 + 255)/256, 256, 0, stream>>>(w_proj, wprojh, wprojl, n4);

  gemm_split<0><<<dim3(MTOT/128, (3*WW)/128), 256, 0, stream>>>(
      xh, xl, wqkvh, wqkvl, b_qkv, WW, 3*WW, nullptr,
      Qhb, Qlb, Khb, Klb, Vtb);

  attn_kernel<<<dim3(BB*HH, SS/64), 256, 0, stream>>>(
      Qhb, Qlb, Khb, Klb, Vtb, Obh, Obl);

  gemm_split<1><<<dim3(MTOT/128, WW/128), 256, 0, stream>>>(
      Obh, Obl, wprojh, wprojl, b_proj, WW, WW, out,
      nullptr, nullptr, nullptr, nullptr, nullptr);
}

// Round 14
// 369.656 us; speedup vs baseline: 1.1325x; 1.1325x over previous
//
#include <hip/hip_runtime.h>
#include <hip/hip_bf16.h>

typedef unsigned short U16;
typedef __attribute__((ext_vector_type(8))) short bf16x8;
typedef __attribute__((ext_vector_type(4))) float f32x4;
typedef __attribute__((ext_vector_type(4))) unsigned short u16x4;

#define BB 2
#define SS 2048
#define WW 1024
#define HH 16
#define CC 64
#define MTOT (BB*SS)                    // 4096
// SCALE = 1/64^0.25; QK_SCALE = SCALE * sqrt(log2(e)) -> logits in log2 units
#define QK_SCALE 0.4246609001440095f

__device__ __forceinline__ U16 f2bf(float f) {
  __hip_bfloat16 b = __float2bfloat16(f);       // native RNE cast
  return *reinterpret_cast<U16*>(&b);
}
__device__ __forceinline__ float bf2f(U16 h) {
  return __uint_as_float(((unsigned int)h) << 16);
}

// async global->LDS, 16B/lane; LDS dest = wave-uniform base + lane*16 (linear!)
// Swizzled layouts via inverse-swizzled per-lane GLOBAL source (rule 21).
#define GLD16(gp, lp) __builtin_amdgcn_global_load_lds( \
    (const __attribute__((address_space(1))) unsigned int*)(gp), \
    (__attribute__((address_space(3))) unsigned int*)(lp), 16, 0, 0)

#define MFMA(a,b,c) __builtin_amdgcn_mfma_f32_16x16x32_bf16(a,b,c,0,0,0)

// ---------------------------------------------------------------- split convert
__global__ void cvt_split(const float* __restrict__ in, U16* __restrict__ hi,
                          U16* __restrict__ lo, int n4) {
  int i = blockIdx.x * blockDim.x + threadIdx.x;
  if (i < n4) {
    float4 v = reinterpret_cast<const float4*>(in)[i];
    float vv[4] = {v.x, v.y, v.z, v.w};
    u16x4 h, l;
#pragma unroll
    for (int j = 0; j < 4; ++j) {
      U16 hb = f2bf(vv[j]);
      h[j] = hb;
      l[j] = f2bf(vv[j] - bf2f(hb));
    }
    reinterpret_cast<u16x4*>(hi)[i] = h;
    reinterpret_cast<u16x4*>(lo)[i] = l;
  }
}

// ---------------------------------------------------------------- split GEMM 128x128, BK=32
// C = (Ah+Al)*(Bh+Bl)^T + bias via Ah*Bh + Ah*Bl + Al*Bh.  ALL four operand
// tiles staged via global_load_lds (round-7 proven structure; lo-direct reverted).
// LDS [128][32] bf16, swizzle blk^=(row>>1)&3 (2-way, free).
template<int EPI>
__global__ __launch_bounds__(256) void gemm_split(
    const U16* __restrict__ Ah, const U16* __restrict__ Al,
    const U16* __restrict__ Bh, const U16* __restrict__ Bl,
    const float* __restrict__ bias, int K, int N,
    float* __restrict__ out,
    U16* __restrict__ Qh, U16* __restrict__ Ql,
    U16* __restrict__ Kh, U16* __restrict__ Kl, U16* __restrict__ Vt)
{
  __shared__ U16 AsH[128*32], AsL[128*32], BsH[128*32], BsL[128*32];
  const int tid  = threadIdx.x;
  const int lane = tid & 63, w = tid >> 6;
  const int wr = w >> 1, wc = w & 1;
  const int g = lane >> 4, lr = lane & 15;
  const int bm = blockIdx.x, bn = blockIdx.y;

  f32x4 acc[4][4] = {};

  for (int k0 = 0; k0 < K; k0 += 32) {
#pragma unroll
    for (int i = 0; i < 2; ++i) {
      const int rowT = i*64 + (tid >> 2);                 // tile row 0..127
      const int sblk = (tid & 3) ^ ((rowT >> 1) & 3);     // inverse-swizzled source block
      const size_t ga = (size_t)(bm*128 + rowT) * K + k0 + sblk*8;
      const size_t gb = (size_t)(bn*128 + rowT) * K + k0 + sblk*8;
      const int lb = i*2048 + w*512;                      // wave-uniform LDS elem base
      GLD16(Ah + ga, &AsH[lb]);
      GLD16(Al + ga, &AsL[lb]);
      GLD16(Bh + gb, &BsH[lb]);
      GLD16(Bl + gb, &BsL[lb]);
    }
    __syncthreads();

    bf16x8 ah[4], al[4], bh[4], bl[4];
#pragma unroll
    for (int mi = 0; mi < 4; ++mi) {
      const int row = wr*64 + mi*16 + lr;
      const int so  = row*32 + ((g ^ ((row >> 1) & 3)) * 8);  // swizzled read
      ah[mi] = *reinterpret_cast<const bf16x8*>(&AsH[so]);
      al[mi] = *reinterpret_cast<const bf16x8*>(&AsL[so]);
    }
#pragma unroll
    for (int ni = 0; ni < 4; ++ni) {
      const int row = wc*64 + ni*16 + lr;
      const int so  = row*32 + ((g ^ ((row >> 1) & 3)) * 8);
      bh[ni] = *reinterpret_cast<const bf16x8*>(&BsH[so]);
      bl[ni] = *reinterpret_cast<const bf16x8*>(&BsL[so]);
    }
#pragma unroll
    for (int ni = 0; ni < 4; ++ni)
#pragma unroll
      for (int mi = 0; mi < 4; ++mi) {
        acc[mi][ni] = MFMA(ah[mi], bh[ni], acc[mi][ni]);
        acc[mi][ni] = MFMA(ah[mi], bl[ni], acc[mi][ni]);
        acc[mi][ni] = MFMA(al[mi], bh[ni], acc[mi][ni]);
      }
    __syncthreads();
  }

  // epilogue; D layout (m89): row = 4*(lane>>4)+reg, col = lane&15
#pragma unroll
  for (int mi = 0; mi < 4; ++mi) {
#pragma unroll
    for (int ni = 0; ni < 4; ++ni) {
#pragma unroll
      for (int r = 0; r < 4; ++r) {
        const int grow = bm*128 + wr*64 + mi*16 + 4*g + r;
        const int gcol = bn*128 + wc*64 + ni*16 + lr;
        const float val = acc[mi][ni][r] + bias[gcol];
        if (EPI == 0) {
          const int b = grow >> 11, s = grow & 2047;
          const int h = gcol / 192;
          const int rem = gcol - h * 192;
          const int t = rem >> 6, c = rem & 63;
          const size_t bh_ = (size_t)(b * HH + h);
          if (t == 2) {
            Vt[(bh_ * CC + c) * SS + s] = f2bf(val);
          } else {
            const float sv = val * QK_SCALE;   // symmetric scale * sqrt(log2e)
            const U16 hb = f2bf(sv);
            const U16 lb = f2bf(sv - bf2f(hb));
            const size_t idx = (bh_ * SS + s) * CC + c;
            if (t == 0) { Qh[idx] = hb; Ql[idx] = lb; }
            else        { Kh[idx] = hb; Kl[idx] = lb; }
          }
        } else {
          out[(size_t)grow * N + gcol] = val;
        }
      }
    }
  }
}

// ---------------------------------------------------------------- flash attention
// grid: (B*H, S/64). 4 waves x 16 q-rows. KV tiles of 64. Logits in log2 units
// (exp2f direct, no LOG2E muls). Always-rescale online softmax (defer-max
// reverted: +16 VGPR / -10% occupancy was net negative, r13).
// K/V LDS tiles [64][64] bf16, swizzle blk^=(row&7).
__global__ __launch_bounds__(256) void attn_kernel(
    const U16* __restrict__ Qh, const U16* __restrict__ Ql,
    const U16* __restrict__ Kh, const U16* __restrict__ Kl,
    const U16* __restrict__ Vtb, U16* __restrict__ Obh, U16* __restrict__ Obl)
{
  __shared__ U16 KsH[64*64];
  __shared__ U16 KsL[64*64];
  __shared__ U16 Vts[64*64];          // [c][s_local]
  __shared__ U16 Ps [4][16*72];       // per-wave P tile, stride 72

  const int tid  = threadIdx.x;
  const int lane = tid & 63, w = tid >> 6;
  const int g = lane >> 4, lr = lane & 15;
  const int bh = blockIdx.x;          // 0..31
  const int qt = blockIdx.y;          // 0..31

  const U16* QhP = Qh  + (size_t)bh * SS * CC;
  const U16* QlP = Ql  + (size_t)bh * SS * CC;
  const U16* KhP = Kh  + (size_t)bh * SS * CC;
  const U16* KlP = Kl  + (size_t)bh * SS * CC;
  const U16* Vh  = Vtb + (size_t)bh * CC * SS;

  const int q0 = qt * 64 + w * 16;

  bf16x8 qfh[2], qfl[2];
#pragma unroll
  for (int kk = 0; kk < 2; ++kk) {
    qfh[kk] = *reinterpret_cast<const bf16x8*>(&QhP[(size_t)(q0 + lr) * CC + kk*32 + g*8]);
    qfl[kk] = *reinterpret_cast<const bf16x8*>(&QlP[(size_t)(q0 + lr) * CC + kk*32 + g*8]);
  }

  float m[4], l[4];
  f32x4 o[4];
#pragma unroll
  for (int r = 0; r < 4; ++r) { m[r] = -1e30f; l[r] = 0.f; }
#pragma unroll
  for (int cs = 0; cs < 4; ++cs) o[cs] = (f32x4){0.f, 0.f, 0.f, 0.f};

  for (int kv = 0; kv < SS; kv += 64) {
#pragma unroll
    for (int i = 0; i < 2; ++i) {
      const int t2   = i*256 + tid;
      const int row  = t2 >> 3;
      const int sblk = (t2 & 7) ^ (row & 7);
      const int lb   = (i*256 + w*64) * 8;
      GLD16(KhP + (size_t)(kv + row) * CC + sblk*8, &KsH[lb]);
      GLD16(KlP + (size_t)(kv + row) * CC + sblk*8, &KsL[lb]);
      GLD16(Vh  + (size_t)row * SS + kv + sblk*8,   &Vts[lb]);
    }
    __syncthreads();

    // S = Q K^T (split)
    f32x4 sacc[4];
#pragma unroll
    for (int ns = 0; ns < 4; ++ns) {
      f32x4 a = {0.f, 0.f, 0.f, 0.f};
      const int krow = ns*16 + lr;
#pragma unroll
      for (int kk = 0; kk < 2; ++kk) {
        const int so = krow*64 + (((kk*4 + g) ^ (krow & 7)) * 8);
        bf16x8 kfh = *reinterpret_cast<const bf16x8*>(&KsH[so]);
        bf16x8 kfl = *reinterpret_cast<const bf16x8*>(&KsL[so]);
        a = MFMA(qfh[kk], kfh, a);
        a = MFMA(qfh[kk], kfl, a);
        a = MFMA(qfl[kk], kfh, a);
      }
      sacc[ns] = a;
    }

    // online softmax (log2 units); D row = 4*g + r, col = ns*16 + lr
    float pr[4][4];
#pragma unroll
    for (int r = 0; r < 4; ++r) {
      float mx = fmaxf(fmaxf(sacc[0][r], sacc[1][r]), fmaxf(sacc[2][r], sacc[3][r]));
#pragma unroll
      for (int off = 1; off < 16; off <<= 1) mx = fmaxf(mx, __shfl_xor(mx, off, 64));
      const float mn   = fmaxf(m[r], mx);
      const float corr = exp2f(m[r] - mn);
      float ps = 0.f;
#pragma unroll
      for (int ns = 0; ns < 4; ++ns) {
        const float p = exp2f(sacc[ns][r] - mn);
        pr[ns][r] = p; ps += p;
      }
#pragma unroll
      for (int off = 1; off < 16; off <<= 1) ps += __shfl_xor(ps, off, 64);
      l[r] = l[r] * corr + ps;
      m[r] = mn;
#pragma unroll
      for (int cs = 0; cs < 4; ++cs) o[cs][r] *= corr;
    }

    // P -> bf16 -> per-wave LDS
#pragma unroll
    for (int ns = 0; ns < 4; ++ns)
#pragma unroll
      for (int r = 0; r < 4; ++r)
        Ps[w][(4*g + r)*72 + ns*16 + lr] = f2bf(pr[ns][r]);
    asm volatile("s_waitcnt lgkmcnt(0)" ::: "memory");
    __builtin_amdgcn_sched_barrier(0);

    // O += P V  (pf cs-invariant: hoisted)
    bf16x8 pf[2];
#pragma unroll
    for (int kk = 0; kk < 2; ++kk)
      pf[kk] = *reinterpret_cast<const bf16x8*>(&Ps[w][lr*72 + kk*32 + g*8]);
#pragma unroll
    for (int cs = 0; cs < 4; ++cs) {
      f32x4 a = o[cs];
      const int vrow = cs*16 + lr;
#pragma unroll
      for (int kk = 0; kk < 2; ++kk) {
        const int so = vrow*64 + (((kk*4 + g) ^ (vrow & 7)) * 8);
        bf16x8 vf = *reinterpret_cast<const bf16x8*>(&Vts[so]);
        a = MFMA(pf[kk], vf, a);
      }
      o[cs] = a;
    }
    __syncthreads();
  }

  // finalize: Ob (hi/lo) at [b][s][h*64+c]
  const int b = bh >> 4, h = bh & 15;
#pragma unroll
  for (int r = 0; r < 4; ++r) {
    const float inv = 1.0f / l[r];
    const int qg = q0 + 4*g + r;
#pragma unroll
    for (int cs = 0; cs < 4; ++cs) {
      const float ov = o[cs][r] * inv;
      const size_t idx = ((size_t)(b*SS + qg)) * WW + h*CC + cs*16 + lr;
      const U16 hb = f2bf(ov);
      Obh[idx] = hb;
      Obl[idx] = f2bf(ov - bf2f(hb));
    }
  }
}

// ---------------------------------------------------------------- launch
extern "C" void kernel_launch(void* const* d_in, const int* in_sizes, int n_in,
                              void* d_out, int out_size, void* d_ws, size_t ws_size,
                              hipStream_t stream)
{
  const float* x      = (const float*)d_in[0];
  const float* w_qkv  = (const float*)d_in[1];
  const float* b_qkv  = (const float*)d_in[2];
  const float* w_proj = (const float*)d_in[3];
  const float* b_proj = (const float*)d_in[4];
  float* out = (float*)d_out;

  U16* ws = (U16*)d_ws;
  U16* xh      = ws;                                   // 4096*1024
  U16* xl      = xh     + (size_t)MTOT*WW;
  U16* wqkvh   = xl     + (size_t)MTOT*WW;             // 3072*1024
  U16* wqkvl   = wqkvh  + (size_t)3*WW*WW;
  U16* wprojh  = wqkvl  + (size_t)3*WW*WW;             // 1024*1024
  U16* wprojl  = wprojh + (size_t)WW*WW;
  U16* Qhb     = wprojl + (size_t)WW*WW;               // [b][h][s][c]
  U16* Qlb     = Qhb    + (size_t)BB*HH*SS*CC;
  U16* Khb     = Qlb    + (size_t)BB*HH*SS*CC;
  U16* Klb     = Khb    + (size_t)BB*HH*SS*CC;
  U16* Vtb     = Klb    + (size_t)BB*HH*SS*CC;         // [b][h][c][s]
  U16* Obh     = xh;                                   // alias x (consumed by GEMM1)
  U16* Obl     = xl;

  int n4 = MTOT*WW/4;
  cvt_split<<<(n4 + 255)/256, 256, 0, stream>>>(x, xh, xl, n4);
  n4 = 3*WW*WW/4;
  cvt_split<<<(n4 + 255)/256, 256, 0, stream>>>(w_qkv, wqkvh, wqkvl, n4);
  n4 = WW*WW/4;
  cvt_split<<<(n4 + 255)/256, 256, 0, stream>>>(w_proj, wprojh, wprojl, n4);

  gemm_split<0><<<dim3(MTOT/128, (3*WW)/128), 256, 0, stream>>>(
      xh, xl, wqkvh, wqkvl, b_qkv, WW, 3*WW, nullptr,
      Qhb, Qlb, Khb, Klb, Vtb);

  attn_kernel<<<dim3(BB*HH, SS/64), 256, 0, stream>>>(
      Qhb, Qlb, Khb, Klb, Vtb, Obh, Obl);

  gemm_split<1><<<dim3(MTOT/128, WW/128), 256, 0, stream>>>(
      Obh, Obl, wprojh, wprojl, b_proj, WW, WW, out,
      nullptr, nullptr, nullptr, nullptr, nullptr);
}

// Round 15
// 356.375 us; speedup vs baseline: 1.1747x; 1.0373x over previous
//
#include <hip/hip_runtime.h>
#include <hip/hip_bf16.h>

typedef unsigned short U16;
typedef __attribute__((ext_vector_type(8))) short bf16x8;
typedef __attribute__((ext_vector_type(4))) float f32x4;
typedef __attribute__((ext_vector_type(4))) unsigned short u16x4;

#define BB 2
#define SS 2048
#define WW 1024
#define HH 16
#define CC 64
#define MTOT (BB*SS)                    // 4096
// SCALE = 1/64^0.25; QK_SCALE = SCALE * sqrt(log2(e)) -> logits in log2 units
#define QK_SCALE 0.4246609001440095f

__device__ __forceinline__ U16 f2bf(float f) {
  __hip_bfloat16 b = __float2bfloat16(f);       // native RNE cast
  return *reinterpret_cast<U16*>(&b);
}
__device__ __forceinline__ float bf2f(U16 h) {
  return __uint_as_float(((unsigned int)h) << 16);
}

// async global->LDS, 16B/lane; LDS dest = wave-uniform base + lane*16 (linear!)
// Swizzled layouts via inverse-swizzled per-lane GLOBAL source (rule 21).
#define GLD16(gp, lp) __builtin_amdgcn_global_load_lds( \
    (const __attribute__((address_space(1))) unsigned int*)(gp), \
    (__attribute__((address_space(3))) unsigned int*)(lp), 16, 0, 0)

#define MFMA(a,b,c) __builtin_amdgcn_mfma_f32_16x16x32_bf16(a,b,c,0,0,0)

// ---------------------------------------------------------------- split convert
__global__ void cvt_split(const float* __restrict__ in, U16* __restrict__ hi,
                          U16* __restrict__ lo, int n4) {
  int i = blockIdx.x * blockDim.x + threadIdx.x;
  if (i < n4) {
    float4 v = reinterpret_cast<const float4*>(in)[i];
    float vv[4] = {v.x, v.y, v.z, v.w};
    u16x4 h, l;
#pragma unroll
    for (int j = 0; j < 4; ++j) {
      U16 hb = f2bf(vv[j]);
      h[j] = hb;
      l[j] = f2bf(vv[j] - bf2f(hb));
    }
    reinterpret_cast<u16x4*>(hi)[i] = h;
    reinterpret_cast<u16x4*>(lo)[i] = l;
  }
}

// ---------------------------------------------------------------- split GEMM 128x64, BK=32
// C = (Ah+Al)*(Bh+Bl)^T + bias via Ah*Bh + Ah*Bl + Al*Bh.
// Tile shrunk 128x128 -> 128x64 (r14): LDS 32->24 KB, grid 3->6 blocks/CU
// (gemm1) / 1->2 (gemm2) for implicit multi-block latency overlap (m114).
// LDS [rows][32] bf16, swizzle blk^=(row>>1)&3 (2-way, free).
template<int EPI>
__global__ __launch_bounds__(256) void gemm_split(
    const U16* __restrict__ Ah, const U16* __restrict__ Al,
    const U16* __restrict__ Bh, const U16* __restrict__ Bl,
    const float* __restrict__ bias, int K, int N,
    float* __restrict__ out,
    U16* __restrict__ Qh, U16* __restrict__ Ql,
    U16* __restrict__ Kh, U16* __restrict__ Kl, U16* __restrict__ Vt)
{
  __shared__ U16 AsH[128*32], AsL[128*32], BsH[64*32], BsL[64*32];
  const int tid  = threadIdx.x;
  const int lane = tid & 63, w = tid >> 6;
  const int wr = w >> 1, wc = w & 1;      // wave tile: 64 rows x 32 cols
  const int g = lane >> 4, lr = lane & 15;
  const int bm = blockIdx.x, bn = blockIdx.y;

  f32x4 acc[4][2] = {};

  for (int k0 = 0; k0 < K; k0 += 32) {
    // A tiles: 128x32 hi+lo, 2 rounds of 256 threads x 16B
#pragma unroll
    for (int i = 0; i < 2; ++i) {
      const int rowT = i*64 + (tid >> 2);
      const int sblk = (tid & 3) ^ ((rowT >> 1) & 3);
      const size_t ga = (size_t)(bm*128 + rowT) * K + k0 + sblk*8;
      const int lb = i*2048 + w*512;
      GLD16(Ah + ga, &AsH[lb]);
      GLD16(Al + ga, &AsL[lb]);
    }
    // B tile: 64x32 hi+lo, 1 round
    {
      const int rowT = tid >> 2;
      const int sblk = (tid & 3) ^ ((rowT >> 1) & 3);
      const size_t gb = (size_t)(bn*64 + rowT) * K + k0 + sblk*8;
      const int lb = w*512;
      GLD16(Bh + gb, &BsH[lb]);
      GLD16(Bl + gb, &BsL[lb]);
    }
    __syncthreads();

    bf16x8 ah[4], al[4], bh[2], bl[2];
#pragma unroll
    for (int mi = 0; mi < 4; ++mi) {
      const int row = wr*64 + mi*16 + lr;
      const int so  = row*32 + ((g ^ ((row >> 1) & 3)) * 8);  // swizzled read
      ah[mi] = *reinterpret_cast<const bf16x8*>(&AsH[so]);
      al[mi] = *reinterpret_cast<const bf16x8*>(&AsL[so]);
    }
#pragma unroll
    for (int ni = 0; ni < 2; ++ni) {
      const int row = wc*32 + ni*16 + lr;
      const int so  = row*32 + ((g ^ ((row >> 1) & 3)) * 8);
      bh[ni] = *reinterpret_cast<const bf16x8*>(&BsH[so]);
      bl[ni] = *reinterpret_cast<const bf16x8*>(&BsL[so]);
    }
#pragma unroll
    for (int ni = 0; ni < 2; ++ni)
#pragma unroll
      for (int mi = 0; mi < 4; ++mi) {
        acc[mi][ni] = MFMA(ah[mi], bh[ni], acc[mi][ni]);
        acc[mi][ni] = MFMA(ah[mi], bl[ni], acc[mi][ni]);
        acc[mi][ni] = MFMA(al[mi], bh[ni], acc[mi][ni]);
      }
    __syncthreads();
  }

  // epilogue; D layout (m89): row = 4*(lane>>4)+reg, col = lane&15
#pragma unroll
  for (int mi = 0; mi < 4; ++mi) {
#pragma unroll
    for (int ni = 0; ni < 2; ++ni) {
#pragma unroll
      for (int r = 0; r < 4; ++r) {
        const int grow = bm*128 + wr*64 + mi*16 + 4*g + r;
        const int gcol = bn*64 + wc*32 + ni*16 + lr;
        const float val = acc[mi][ni][r] + bias[gcol];
        if (EPI == 0) {
          const int b = grow >> 11, s = grow & 2047;
          const int h = gcol / 192;
          const int rem = gcol - h * 192;
          const int t = rem >> 6, c = rem & 63;
          const size_t bh_ = (size_t)(b * HH + h);
          if (t == 2) {
            Vt[(bh_ * CC + c) * SS + s] = f2bf(val);
          } else {
            const float sv = val * QK_SCALE;   // symmetric scale * sqrt(log2e)
            const U16 hb = f2bf(sv);
            const U16 lb = f2bf(sv - bf2f(hb));
            const size_t idx = (bh_ * SS + s) * CC + c;
            if (t == 0) { Qh[idx] = hb; Ql[idx] = lb; }
            else        { Kh[idx] = hb; Kl[idx] = lb; }
          }
        } else {
          out[(size_t)grow * N + gcol] = val;
        }
      }
    }
  }
}

// ---------------------------------------------------------------- flash attention
// grid: (B*H, S/64). 4 waves x 16 q-rows. KV tiles of 64. Logits in log2 units
// (exp2f direct). Always-rescale online softmax (defer-max reverted, r13).
// K/V LDS tiles [64][64] bf16, swizzle blk^=(row&7). UNCHANGED from r14 best.
__global__ __launch_bounds__(256) void attn_kernel(
    const U16* __restrict__ Qh, const U16* __restrict__ Ql,
    const U16* __restrict__ Kh, const U16* __restrict__ Kl,
    const U16* __restrict__ Vtb, U16* __restrict__ Obh, U16* __restrict__ Obl)
{
  __shared__ U16 KsH[64*64];
  __shared__ U16 KsL[64*64];
  __shared__ U16 Vts[64*64];          // [c][s_local]
  __shared__ U16 Ps [4][16*72];       // per-wave P tile, stride 72

  const int tid  = threadIdx.x;
  const int lane = tid & 63, w = tid >> 6;
  const int g = lane >> 4, lr = lane & 15;
  const int bh = blockIdx.x;          // 0..31
  const int qt = blockIdx.y;          // 0..31

  const U16* QhP = Qh  + (size_t)bh * SS * CC;
  const U16* QlP = Ql  + (size_t)bh * SS * CC;
  const U16* KhP = Kh  + (size_t)bh * SS * CC;
  const U16* KlP = Kl  + (size_t)bh * SS * CC;
  const U16* Vh  = Vtb + (size_t)bh * CC * SS;

  const int q0 = qt * 64 + w * 16;

  bf16x8 qfh[2], qfl[2];
#pragma unroll
  for (int kk = 0; kk < 2; ++kk) {
    qfh[kk] = *reinterpret_cast<const bf16x8*>(&QhP[(size_t)(q0 + lr) * CC + kk*32 + g*8]);
    qfl[kk] = *reinterpret_cast<const bf16x8*>(&QlP[(size_t)(q0 + lr) * CC + kk*32 + g*8]);
  }

  float m[4], l[4];
  f32x4 o[4];
#pragma unroll
  for (int r = 0; r < 4; ++r) { m[r] = -1e30f; l[r] = 0.f; }
#pragma unroll
  for (int cs = 0; cs < 4; ++cs) o[cs] = (f32x4){0.f, 0.f, 0.f, 0.f};

  for (int kv = 0; kv < SS; kv += 64) {
#pragma unroll
    for (int i = 0; i < 2; ++i) {
      const int t2   = i*256 + tid;
      const int row  = t2 >> 3;
      const int sblk = (t2 & 7) ^ (row & 7);
      const int lb   = (i*256 + w*64) * 8;
      GLD16(KhP + (size_t)(kv + row) * CC + sblk*8, &KsH[lb]);
      GLD16(KlP + (size_t)(kv + row) * CC + sblk*8, &KsL[lb]);
      GLD16(Vh  + (size_t)row * SS + kv + sblk*8,   &Vts[lb]);
    }
    __syncthreads();

    // S = Q K^T (split)
    f32x4 sacc[4];
#pragma unroll
    for (int ns = 0; ns < 4; ++ns) {
      f32x4 a = {0.f, 0.f, 0.f, 0.f};
      const int krow = ns*16 + lr;
#pragma unroll
      for (int kk = 0; kk < 2; ++kk) {
        const int so = krow*64 + (((kk*4 + g) ^ (krow & 7)) * 8);
        bf16x8 kfh = *reinterpret_cast<const bf16x8*>(&KsH[so]);
        bf16x8 kfl = *reinterpret_cast<const bf16x8*>(&KsL[so]);
        a = MFMA(qfh[kk], kfh, a);
        a = MFMA(qfh[kk], kfl, a);
        a = MFMA(qfl[kk], kfh, a);
      }
      sacc[ns] = a;
    }

    // online softmax (log2 units); D row = 4*g + r, col = ns*16 + lr
    float pr[4][4];
#pragma unroll
    for (int r = 0; r < 4; ++r) {
      float mx = fmaxf(fmaxf(sacc[0][r], sacc[1][r]), fmaxf(sacc[2][r], sacc[3][r]));
#pragma unroll
      for (int off = 1; off < 16; off <<= 1) mx = fmaxf(mx, __shfl_xor(mx, off, 64));
      const float mn   = fmaxf(m[r], mx);
      const float corr = exp2f(m[r] - mn);
      float ps = 0.f;
#pragma unroll
      for (int ns = 0; ns < 4; ++ns) {
        const float p = exp2f(sacc[ns][r] - mn);
        pr[ns][r] = p; ps += p;
      }
#pragma unroll
      for (int off = 1; off < 16; off <<= 1) ps += __shfl_xor(ps, off, 64);
      l[r] = l[r] * corr + ps;
      m[r] = mn;
#pragma unroll
      for (int cs = 0; cs < 4; ++cs) o[cs][r] *= corr;
    }

    // P -> bf16 -> per-wave LDS
#pragma unroll
    for (int ns = 0; ns < 4; ++ns)
#pragma unroll
      for (int r = 0; r < 4; ++r)
        Ps[w][(4*g + r)*72 + ns*16 + lr] = f2bf(pr[ns][r]);
    asm volatile("s_waitcnt lgkmcnt(0)" ::: "memory");
    __builtin_amdgcn_sched_barrier(0);

    // O += P V  (pf cs-invariant: hoisted)
    bf16x8 pf[2];
#pragma unroll
    for (int kk = 0; kk < 2; ++kk)
      pf[kk] = *reinterpret_cast<const bf16x8*>(&Ps[w][lr*72 + kk*32 + g*8]);
#pragma unroll
    for (int cs = 0; cs < 4; ++cs) {
      f32x4 a = o[cs];
      const int vrow = cs*16 + lr;
#pragma unroll
      for (int kk = 0; kk < 2; ++kk) {
        const int so = vrow*64 + (((kk*4 + g) ^ (vrow & 7)) * 8);
        bf16x8 vf = *reinterpret_cast<const bf16x8*>(&Vts[so]);
        a = MFMA(pf[kk], vf, a);
      }
      o[cs] = a;
    }
    __syncthreads();
  }

  // finalize: Ob (hi/lo) at [b][s][h*64+c]
  const int b = bh >> 4, h = bh & 15;
#pragma unroll
  for (int r = 0; r < 4; ++r) {
    const float inv = 1.0f / l[r];
    const int qg = q0 + 4*g + r;
#pragma unroll
    for (int cs = 0; cs < 4; ++cs) {
      const float ov = o[cs][r] * inv;
      const size_t idx = ((size_t)(b*SS + qg)) * WW + h*CC + cs*16 + lr;
      const U16 hb = f2bf(ov);
      Obh[idx] = hb;
      Obl[idx] = f2bf(ov - bf2f(hb));
    }
  }
}

// ---------------------------------------------------------------- launch
extern "C" void kernel_launch(void* const* d_in, const int* in_sizes, int n_in,
                              void* d_out, int out_size, void* d_ws, size_t ws_size,
                              hipStream_t stream)
{
  const float* x      = (const float*)d_in[0];
  const float* w_qkv  = (const float*)d_in[1];
  const float* b_qkv  = (const float*)d_in[2];
  const float* w_proj = (const float*)d_in[3];
  const float* b_proj = (const float*)d_in[4];
  float* out = (float*)d_out;

  U16* ws = (U16*)d_ws;
  U16* xh      = ws;                                   // 4096*1024
  U16* xl      = xh     + (size_t)MTOT*WW;
  U16* wqkvh   = xl     + (size_t)MTOT*WW;             // 3072*1024
  U16* wqkvl   = wqkvh  + (size_t)3*WW*WW;
  U16* wprojh  = wqkvl  + (size_t)3*WW*WW;             // 1024*1024
  U16* wprojl  = wprojh + (size_t)WW*WW;
  U16* Qhb     = wprojl + (size_t)WW*WW;               // [b][h][s][c]
  U16* Qlb     = Qhb    + (size_t)BB*HH*SS*CC;
  U16* Khb     = Qlb    + (size_t)BB*HH*SS*CC;
  U16* Klb     = Khb    + (size_t)BB*HH*SS*CC;
  U16* Vtb     = Klb    + (size_t)BB*HH*SS*CC;         // [b][h][c][s]
  U16* Obh     = xh;                                   // alias x (consumed by GEMM1)
  U16* Obl     = xl;

  int n4 = MTOT*WW/4;
  cvt_split<<<(n4 + 255)/256, 256, 0, stream>>>(x, xh, xl, n4);
  n4 = 3*WW*WW/4;
  cvt_split<<<(n4 + 255)/256, 256, 0, stream>>>(w_qkv, wqkvh, wqkvl, n4);
  n4 = WW*WW/4;
  cvt_split<<<(n4 + 255)/256, 256, 0, stream>>>(w_proj, wprojh, wprojl, n4);

  gemm_split<0><<<dim3(MTOT/128, (3*WW)/64), 256, 0, stream>>>(
      xh, xl, wqkvh, wqkvl, b_qkv, WW, 3*WW, nullptr,
      Qhb, Qlb, Khb, Klb, Vtb);

  attn_kernel<<<dim3(BB*HH, SS/64), 256, 0, stream>>>(
      Qhb, Qlb, Khb, Klb, Vtb, Obh, Obl);

  gemm_split<1><<<dim3(MTOT/128, WW/64), 256, 0, stream>>>(
      Obh, Obl, wprojh, wprojl, b_proj, WW, WW, out,
      nullptr, nullptr, nullptr, nullptr, nullptr);
}